// Round 9
// baseline (103.135 us; speedup 1.0000x reference)
//
#include <hip/hip_runtime.h>

// images=8, patches=3600(=60*60), hor_f=64, ver_f=25(=5*5), 64x64 px, k=5
#define OH     60
#define NIMG   8
#define HF     64
#define VF     25
#define NPATCH 3600
#define CDIM   1600                  // HF*VF

// ---- fold: grid (hg 8, strip 12, im 8) = 768 blocks, 512 threads ----
#define FH   8                       // h channels per block
#define FC   (FH * VF)               // 200 c values
#define SPI  5                       // pi rows per strip
#define PJS  64                      // pj stride (XOR-swizzled)
#define NSTRIP 12
#define SROWS  9                     // SPI + 4 halo rows

__global__ __launch_bounds__(512, 6) void fold_kernel(const float* __restrict__ x,
                                                      float* __restrict__ slab) {
    __shared__ float lb[FC * PJS];   // 51.2 KB
    const int hg = blockIdx.x, strip = blockIdx.y, im = blockIdx.z;
    const int t = threadIdx.x;
    const int h0 = hg * FH;
    const int pi0 = strip * SPI;
    const int j = t & 63, g = t >> 6;          // g = local h (0..7)

    float acc[SROWS];
#pragma unroll
    for (int k = 0; k < SROWS; ++k) acc[k] = 0.f;

    const float* xb = x + ((size_t)im * NPATCH + (size_t)pi0 * OH) * CDIM + h0 * VF;

    int off_g[6], off_l[6];
#pragma unroll
    for (int k = 0; k < 6; ++k) {
        int u = t + 512 * k;
        if (u < 3000) {
            int pj = u / 50, c4 = u - 50 * pj;
            off_g[k] = pj * CDIM + (c4 << 2);
            off_l[k] = (c4 << 8) + (pj ^ (c4 & 31));
        }
    }

    float4 stg[6];
#pragma unroll
    for (int k = 0; k < 6; ++k)
        if (t + 512 * k < 3000)
            stg[k] = *reinterpret_cast<const float4*>(xb + off_g[k]);

#pragma unroll
    for (int row = 0; row < SPI; ++row) {
        if (row) __syncthreads();
#pragma unroll
        for (int k = 0; k < 6; ++k)
            if (t + 512 * k < 3000) {
                float4 v = stg[k];
                int a = off_l[k];
                lb[a]           = v.x;
                lb[a + PJS]     = v.y;
                lb[a + 2 * PJS] = v.z;
                lb[a + 3 * PJS] = v.w;
            }
        if (row + 1 < SPI) {
#pragma unroll
            for (int k = 0; k < 6; ++k)
                if (t + 512 * k < 3000)
                    stg[k] = *reinterpret_cast<const float4*>(
                        xb + (size_t)(row + 1) * OH * CDIM + off_g[k]);
        }
        __syncthreads();
#pragma unroll
        for (int di = 0; di < 5; ++di) {
#pragma unroll
            for (int dj = 0; dj < 5; ++dj) {
                int c = g * VF + di * 5 + dj;
                int pjr = j - dj;
                if ((unsigned)pjr < 60u)
                    acc[row + di] += lb[c * PJS + (pjr ^ ((c >> 2) & 31))];
            }
        }
    }

    float* sb = slab + (((size_t)(strip * 8 + im) * 64 + h0 + g) * SROWS) * 64 + j;
#pragma unroll
    for (int il = 0; il < SROWS; ++il) sb[il * 64] = acc[il];
}

// ---- unfold v3: grid (pjq 4, pi 60, im 8) = 1920 blocks, 256 threads ----
// Block owns ALL 64 ch of 15 patches (pj0..pj0+14) -> 96 KB CONTIGUOUS out writes.
// li[R=ch*5+di][jloc], row stride JP=25 (odd -> bank spread, additive LUT).
#define JP 25

__global__ __launch_bounds__(256) void unfold_kernel(const float* __restrict__ slab,
                                                     float* __restrict__ out) {
    __shared__ float li[320 * JP];             // 32.0 KB
    __shared__ ushort4 lut[400];               // 3.2 KB
    const int pjq = blockIdx.x;                // 0..3
    const int pi  = blockIdx.y;                // 0..59
    const int im  = blockIdx.z;
    const int t   = threadIdx.x;
    const int pj0 = pjq * 15;
    const int jstart = pj0 & ~3;               // 0,12,28,44 (f4-aligned)
    const int pbase0 = pj0 - jstart;           // 0,3,2,1

    for (int u = t; u < 400; u += 256) {       // f4-slot r -> 4 ushort offsets R*JP+dj
        ushort4 e;
        unsigned short* ep = &e.x;
#pragma unroll
        for (int k = 0; k < 4; ++k) {
            int fl = 4 * u + k;                // = ho*25 + v
            int ho = fl / 25, v = fl - 25 * ho;
            int di = v / 5, dj = v - 5 * di;
            ep[k] = (unsigned short)((ho * 5 + di) * JP + dj);
        }
        lut[u] = e;
    }

    // stage: 64 ch x 5 di x 6 f4 (jloc 0..23), strip-summed, pre-scaled by 1/(ci*cj)
    const int jcap = 60 - jstart;              // clamp keeps f4 load in row (mult of 4)
    for (int u = t; u < 1920; u += 256) {
        int ch = u / 30, rem = u - 30 * ch;
        int di = rem / 6, j4 = rem - 6 * di;
        int jl = j4 << 2;
        int jr = min(jl, jcap);                // read addr (clamped dup, unused slots)
        int i = pi + di;
        int s_hi = min(i / 5, NSTRIP - 1);
        int s_lo = (i <= 8) ? 0 : (i - 4) / 5;
        const float* pa = slab +
            (((size_t)(s_lo * 8 + im) * 64 + ch) * SROWS + (i - 5 * s_lo)) * 64 + jstart + jr;
        float4 v = *reinterpret_cast<const float4*>(pa);
        if (s_hi != s_lo) {
            const float* pb = slab +
                (((size_t)(s_hi * 8 + im) * 64 + ch) * SROWS + (i - 5 * s_hi)) * 64 + jstart + jr;
            float4 w = *reinterpret_cast<const float4*>(pb);
            v.x += w.x; v.y += w.y; v.z += w.z; v.w += w.w;
        }
        float ri = 1.0f / (float)min(min(i + 1, 64 - i), 5);
        int jj = jstart + jr;
        float4 w;
        w.x = v.x * ri * (1.0f / (float)min(min(jj + 1, 64 - jj), 5));
        w.y = v.y * ri * (1.0f / (float)min(min(jj + 2, 63 - jj), 5));
        w.z = v.z * ri * (1.0f / (float)min(min(jj + 3, 62 - jj), 5));
        w.w = v.w * ri * (1.0f / (float)min(min(jj + 4, 61 - jj), 5));
        int a = (ch * 5 + di) * JP + jl;       // write to ORIGINAL slot jl
        li[a]     = w.x;
        li[a + 1] = w.y;
        li[a + 2] = w.z;
        li[a + 3] = w.w;
    }
    __syncthreads();

    // emit: 15 pj x 400 f4 (64h x 25v per pj) -> 96 KB contiguous per block
    float* ob = out + ((size_t)im * NPATCH + (size_t)pi * OH + pj0) * CDIM;
    for (int u = t; u < 6000; u += 256) {
        int pjl = u / 400, r = u - 400 * pjl;
        ushort4 e = lut[r];
        int pb = pbase0 + pjl;
        float4 o;
        o.x = li[e.x + pb];
        o.y = li[e.y + pb];
        o.z = li[e.z + pb];
        o.w = li[e.w + pb];
        *reinterpret_cast<float4*>(ob + (size_t)pjl * CDIM + 4 * r) = o;
    }
}

extern "C" void kernel_launch(void* const* d_in, const int* in_sizes, int n_in,
                              void* d_out, int out_size, void* d_ws, size_t ws_size,
                              hipStream_t stream) {
    const float* x = (const float*)d_in[0];
    float* slab = (float*)d_ws;                // 12*8*64*9*64 fl = 14.2 MB
    float* out  = (float*)d_out;

    fold_kernel<<<dim3(8, NSTRIP, NIMG), 512, 0, stream>>>(x, slab);   // 768 blocks
    unfold_kernel<<<dim3(4, OH, NIMG), 256, 0, stream>>>(slab, out);   // 1920 blocks

    (void)out_size; (void)ws_size; (void)in_sizes; (void)n_in;
}